// Round 8
// baseline (803.706 us; speedup 1.0000x reference)
//
#include <hip/hip_runtime.h>

#define N_NODES 50000
#define N_EDGES 800000

typedef __attribute__((ext_vector_type(8))) short short8;
typedef __attribute__((ext_vector_type(4))) float f32x4;
typedef __attribute__((ext_vector_type(4))) unsigned short u16x4;

__device__ inline unsigned short f2b(float f) {
  union { float f; unsigned int u; } c; c.f = f;
  unsigned int u = c.u;
  u += 0x7FFF + ((u >> 16) & 1);   // round-to-nearest-even
  return (unsigned short)(u >> 16);
}
__device__ inline float b2f_lo(unsigned int u) {
  union { unsigned int u; float f; } c; c.u = u << 16; return c.f;
}
__device__ inline float b2f_hi(unsigned int u) {
  union { unsigned int u; float f; } c; c.u = u & 0xFFFF0000u; return c.f;
}

// ---------------- graph preprocessing ----------------
// edge_index arrives as int32 [2][E]

__global__ void k_deg(const int* __restrict__ ei, int* __restrict__ deg) {
  int e = blockIdx.x * 256 + threadIdx.x;
  if (e < N_EDGES) atomicAdd(&deg[ei[N_EDGES + e]], 1);
}

__global__ void k_dinv(const int* __restrict__ deg, float* __restrict__ dinv) {
  int n = blockIdx.x * 256 + threadIdx.x;
  if (n < N_NODES) dinv[n] = rsqrtf((float)(deg[n] + 1));
}

// single-block shfl-based exclusive scan
__global__ void k_scan(const int* __restrict__ cnt, int* __restrict__ rowptr) {
  __shared__ int wsum[16];
  int tid = threadIdx.x, lane = tid & 63, wv = tid >> 6;
  int carry = 0;
  for (int base = 0; base < N_NODES; base += 1024) {
    int i = base + tid;
    int v = (i < N_NODES) ? cnt[i] : 0;
    int s = v;
#pragma unroll
    for (int off = 1; off < 64; off <<= 1) {
      int u = __shfl_up(s, off, 64);
      if (lane >= off) s += u;
    }
    if (lane == 63) wsum[wv] = s;
    __syncthreads();
    int ws = (lane < 16) ? wsum[lane] : 0;
#pragma unroll
    for (int off = 1; off < 16; off <<= 1) {
      int u = __shfl_up(ws, off, 64);
      if (lane >= off && lane < 16) ws += u;
    }
    int wOff = (wv == 0) ? 0 : __shfl(ws, wv - 1, 64);
    int total = __shfl(ws, 15, 64);
    if (i < N_NODES) rowptr[i] = carry + wOff + (s - v);
    carry += total;
    __syncthreads();
  }
  if (tid == 0) rowptr[N_NODES] = carry;
}

__global__ void k_fill(const int* __restrict__ ei, const int* __restrict__ rowptr,
                       int* __restrict__ cur, int* __restrict__ csr) {
  int e = blockIdx.x * 256 + threadIdx.x;
  if (e < N_EDGES) {
    int d = ei[N_EDGES + e];
    int p = atomicAdd(&cur[d], 1);
    csr[rowptr[d] + p] = ei[e];
  }
}

// x fp32 -> bf16
__global__ void k_cvt(const float* __restrict__ x, unsigned short* __restrict__ xb) {
  int i = blockIdx.x * 256 + threadIdx.x;
  const float4* x4 = (const float4*)x;
  if (i < N_NODES * 128 / 4) {
    float4 v = x4[i];
    ushort4 o; o.x = f2b(v.x); o.y = f2b(v.y); o.z = f2b(v.z); o.w = f2b(v.w);
    ((ushort4*)xb)[i] = o;
  }
}

// ---------------- B packing ----------------
// Chunked layout (gemm_c): unit = ((chunk*KS + s)*128 + col)*4 + grp
// holds W[k = s*32+grp*8+j][gcol = chunk*128+col], j=0..7; zero if gcol>=N.

__global__ void k_packW(const float* __restrict__ W, unsigned short* __restrict__ Bp,
                        int KS, int N) {
  int idx = blockIdx.x * 256 + threadIdx.x;
  int units = ((N + 127) / 128) * KS * 512;
  if (idx >= units) return;
  int grp = idx & 3, col = (idx >> 2) & 127;
  int rest = idx >> 9;
  int s = rest % KS, chunk = rest / KS;
  int gcol = chunk * 128 + col, k0 = s * 32 + grp * 8;
  unsigned short o[8];
#pragma unroll
  for (int j = 0; j < 8; ++j)
    o[j] = (gcol < N) ? f2b(W[(size_t)(k0 + j) * N + gcol]) : 0;
  *(short8*)(Bp + (size_t)idx * 8) = *(short8*)o;
}

// heads: FLAT layout for gemm_h: unit = (s*3200 + gcol)*4 + grp
// packed col space: [0,30)=type [30,55)=school [55,75)=time 75=pad0
// [76,3076)=author (author base 76 => author offsets are 4-float aligned)
__global__ void k_packH(const float* __restrict__ Wt, const float* __restrict__ Ws,
                        const float* __restrict__ Wf, const float* __restrict__ Wa,
                        const float* __restrict__ bt, const float* __restrict__ bs,
                        const float* __restrict__ bfv, const float* __restrict__ ba,
                        unsigned short* __restrict__ Bp, float* __restrict__ bcat) {
  int idx = blockIdx.x * 256 + threadIdx.x;  // 3200*256/8 = 102400 units
  if (idx < 102400) {
    int grp = idx & 3;
    int rest = idx >> 2;          // 0..25599
    int gcol = rest % 3200;
    int s = rest / 3200;          // 0..7
    int k0 = s * 32 + grp * 8;
    const float* W = Wt; int ld = 30, c = 0;
    bool ok = true;
    if (gcol < 30)                        { W = Wt; ld = 30;   c = gcol; }
    else if (gcol < 55)                   { W = Ws; ld = 25;   c = gcol - 30; }
    else if (gcol < 75)                   { W = Wf; ld = 20;   c = gcol - 55; }
    else if (gcol >= 76 && gcol < 3076)   { W = Wa; ld = 3000; c = gcol - 76; }
    else                                  { ok = false; }
    unsigned short o[8];
#pragma unroll
    for (int j = 0; j < 8; ++j)
      o[j] = ok ? f2b(W[(size_t)(k0 + j) * ld + c]) : 0;
    *(short8*)(Bp + (size_t)idx * 8) = *(short8*)o;
  }
  if (idx < 3200) {
    float v = 0.f;
    if (idx < 30)                      v = bt[idx];
    else if (idx < 55)                 v = bs[idx - 30];
    else if (idx < 75)                 v = bfv[idx - 55];
    else if (idx >= 76 && idx < 3076)  v = ba[idx - 76];
    bcat[idx] = v;
  }
}

// ---------------- aggregation (wave per node, 4 waves/block, x4 unroll) ----

__global__ void k_agg1(const unsigned short* __restrict__ xb, const float* __restrict__ dinv,
                       const int* __restrict__ rowptr, const int* __restrict__ csr,
                       unsigned short* __restrict__ A1) {
  int n = blockIdx.x * 4 + (threadIdx.x >> 6);
  if (n >= N_NODES) return;
  int l = threadIdx.x & 63;
  float dn = dinv[n];
  const unsigned int* x2 = (const unsigned int*)xb;
  unsigned int sv = x2[(size_t)n * 64 + l];
  float a0 = b2f_lo(sv) * dn * dn, a1 = b2f_hi(sv) * dn * dn;
  int e = rowptr[n], e1 = rowptr[n + 1];
  for (; e + 4 <= e1; e += 4) {
    int s0 = csr[e], s1 = csr[e + 1], s2 = csr[e + 2], s3 = csr[e + 3];
    float c0 = dinv[s0] * dn, c1 = dinv[s1] * dn, c2 = dinv[s2] * dn, c3 = dinv[s3] * dn;
    unsigned int v0 = x2[(size_t)s0 * 64 + l];
    unsigned int v1 = x2[(size_t)s1 * 64 + l];
    unsigned int v2 = x2[(size_t)s2 * 64 + l];
    unsigned int v3 = x2[(size_t)s3 * 64 + l];
    a0 += b2f_lo(v0) * c0 + b2f_lo(v1) * c1 + b2f_lo(v2) * c2 + b2f_lo(v3) * c3;
    a1 += b2f_hi(v0) * c0 + b2f_hi(v1) * c1 + b2f_hi(v2) * c2 + b2f_hi(v3) * c3;
  }
  for (; e < e1; ++e) {
    int s = csr[e];
    float c = dinv[s] * dn;
    unsigned int v = x2[(size_t)s * 64 + l];
    a0 += b2f_lo(v) * c; a1 += b2f_hi(v) * c;
  }
  unsigned int pk = (unsigned int)f2b(a0) | ((unsigned int)f2b(a1) << 16);
  ((unsigned int*)A1)[(size_t)n * 64 + l] = pk;
}

__global__ void k_agg2(const unsigned short* __restrict__ t, const float* __restrict__ dinv,
                       const int* __restrict__ rowptr, const int* __restrict__ csr,
                       const float* __restrict__ b2, unsigned short* __restrict__ g) {
  int n = blockIdx.x * 4 + (threadIdx.x >> 6);
  if (n >= N_NODES) return;
  int l = threadIdx.x & 63;
  float dn = dinv[n];
  const uint2* t4 = (const uint2*)t;
  uint2 sv = t4[(size_t)n * 64 + l];
  float a0 = b2f_lo(sv.x) * dn * dn, a1 = b2f_hi(sv.x) * dn * dn;
  float a2 = b2f_lo(sv.y) * dn * dn, a3 = b2f_hi(sv.y) * dn * dn;
  int e = rowptr[n], e1 = rowptr[n + 1];
  for (; e + 4 <= e1; e += 4) {
    int s0 = csr[e], s1 = csr[e + 1], s2 = csr[e + 2], s3 = csr[e + 3];
    float c0 = dinv[s0] * dn, c1 = dinv[s1] * dn, c2 = dinv[s2] * dn, c3 = dinv[s3] * dn;
    uint2 v0 = t4[(size_t)s0 * 64 + l];
    uint2 v1 = t4[(size_t)s1 * 64 + l];
    uint2 v2 = t4[(size_t)s2 * 64 + l];
    uint2 v3 = t4[(size_t)s3 * 64 + l];
    a0 += b2f_lo(v0.x) * c0 + b2f_lo(v1.x) * c1 + b2f_lo(v2.x) * c2 + b2f_lo(v3.x) * c3;
    a1 += b2f_hi(v0.x) * c0 + b2f_hi(v1.x) * c1 + b2f_hi(v2.x) * c2 + b2f_hi(v3.x) * c3;
    a2 += b2f_lo(v0.y) * c0 + b2f_lo(v1.y) * c1 + b2f_lo(v2.y) * c2 + b2f_lo(v3.y) * c3;
    a3 += b2f_hi(v0.y) * c0 + b2f_hi(v1.y) * c1 + b2f_hi(v2.y) * c2 + b2f_hi(v3.y) * c3;
  }
  for (; e < e1; ++e) {
    int s = csr[e];
    float c = dinv[s] * dn;
    uint2 v = t4[(size_t)s * 64 + l];
    a0 += b2f_lo(v.x) * c; a1 += b2f_hi(v.x) * c;
    a2 += b2f_lo(v.y) * c; a3 += b2f_hi(v.y) * c;
  }
  int d0 = l * 4;
  a0 += b2[d0]; a1 += b2[d0 + 1]; a2 += b2[d0 + 2]; a3 += b2[d0 + 3];
  ushort4 o; o.x = f2b(a0); o.y = f2b(a1); o.z = f2b(a2); o.w = f2b(a3);
  ((ushort4*)g)[(size_t)n * 64 + l] = o;
}

// ---------------- gemm_c: 64x128-tile GEMM for layer1/layer2 (unchanged) ----

template <int KSTEPS, int NCHUNKS, int EPI>
__global__ __launch_bounds__(256)
void gemm_c(const unsigned short* __restrict__ A, const unsigned short* __restrict__ Bp,
            const float* __restrict__ bias, void* __restrict__ out, int M, int npanels) {
  __shared__ float lt[32][132];
  const int K = KSTEPS * 32;
  int nwg = npanels * NCHUNKS;
  int orig = blockIdx.x;
  int q = nwg >> 3, r = nwg & 7, xcd = orig & 7;
  int l = (xcd < r ? xcd * (q + 1) : r * (q + 1) + (xcd - r) * q) + (orig >> 3);
  int panel = l / NCHUNKS, chunk = l - panel * NCHUNKS;
  int tid = threadIdx.x, lane = tid & 63, w = tid >> 6;
  int ln = lane & 15, grp = lane >> 4;
  int row0 = panel * 64;

  int arow[4];
#pragma unroll
  for (int m = 0; m < 4; ++m) {
    int gr = row0 + m * 16 + ln;
    arow[m] = gr < M ? gr : M - 1;
  }

  f32x4 acc[4][2];
  f32x4 z = {0.f, 0.f, 0.f, 0.f};
#pragma unroll
  for (int m = 0; m < 4; ++m) { acc[m][0] = z; acc[m][1] = z; }

#pragma unroll 4
  for (int s = 0; s < KSTEPS; ++s) {
    short8 bfr[2];
#pragma unroll
    for (int n = 0; n < 2; ++n) {
      size_t unit = ((size_t)(chunk * KSTEPS + s) * 128 + (w * 32 + n * 16 + ln)) * 4 + grp;
      bfr[n] = *(const short8*)(Bp + unit * 8);
    }
    short8 am[4];
#pragma unroll
    for (int m = 0; m < 4; ++m)
      am[m] = *(const short8*)(A + (size_t)arow[m] * K + s * 32 + grp * 8);
#pragma unroll
    for (int m = 0; m < 4; ++m)
#pragma unroll
      for (int n = 0; n < 2; ++n)
        acc[m][n] = __builtin_amdgcn_mfma_f32_16x16x32_bf16(am[m], bfr[n], acc[m][n], 0, 0, 0);
  }

  int c0 = chunk * 128;
  float bv[2];
#pragma unroll
  for (int n = 0; n < 2; ++n)
    bv[n] = (EPI == 1) ? 0.f : bias[c0 + w * 32 + n * 16 + ln];

#pragma unroll
  for (int half = 0; half < 2; ++half) {
    if (half) __syncthreads();
#pragma unroll
    for (int n = 0; n < 2; ++n) {
#pragma unroll
      for (int mm = 0; mm < 2; ++mm) {
        int m = half * 2 + mm;
#pragma unroll
        for (int rr = 0; rr < 4; ++rr) {
          float v = acc[m][n][rr] + bv[n];
          if (EPI == 0) v = v > 0.f ? v : 0.f;
          lt[mm * 16 + grp * 4 + rr][w * 32 + n * 16 + ln] = v;
        }
      }
    }
    __syncthreads();

    int col4 = tid & 31, rowi = tid >> 5;
#pragma unroll
    for (int rr = 0; rr < 4; ++rr) {
      int rw = rr * 8 + rowi;
      int grow = row0 + half * 32 + rw;
      if (grow >= M) continue;
      f32x4 v = *(const f32x4*)&lt[rw][col4 * 4];
      const int NOUT = NCHUNKS * 128;
      u16x4 b;
      b[0] = f2b(v[0]); b[1] = f2b(v[1]); b[2] = f2b(v[2]); b[3] = f2b(v[3]);
      *(u16x4*)((unsigned short*)out + (size_t)grow * NOUT + c0 + col4 * 4) = b;
    }
  }
}

// ---------------- gemm_h: heads GEMM, 16 rows x full 3200 cols per block ----
// 512 threads / 8 waves; wave w owns tile-slot w of each 128-col strip ->
// acc[25]. Block output = 16 x 3000 fp32 = 192 KB CONTIGUOUS region, stored
// strip-by-strip in ascending address order: DRAM-page-sequential within the
// block (H-page experiment). Double-buffered lt, 1 barrier/strip.

__global__ __launch_bounds__(512)
void gemm_h(const unsigned short* __restrict__ A, const unsigned short* __restrict__ Bp,
            const float* __restrict__ bias, float* __restrict__ out) {
  __shared__ float lt[2][16][132];
  const int nwg = N_NODES / 16;  // 3125
  int orig = blockIdx.x;
  int q = nwg >> 3, r = nwg & 7, xcd = orig & 7;
  int pan = (xcd < r ? xcd * (q + 1) : r * (q + 1) + (xcd - r) * q) + (orig >> 3);
  int tid = threadIdx.x, lane = tid & 63, w = tid >> 6;
  int ln = lane & 15, grp = lane >> 4;
  int row0 = pan * 16;

  // A-frags: row = ln, k = s*32 + grp*8 .. +8  (same lane->k map as B pack)
  short8 af[8];
#pragma unroll
  for (int s = 0; s < 8; ++s)
    af[s] = *(const short8*)(A + (size_t)(row0 + ln) * 256 + s * 32 + grp * 8);

  f32x4 acc[25];
  f32x4 z = {0.f, 0.f, 0.f, 0.f};
#pragma unroll
  for (int t = 0; t < 25; ++t) acc[t] = z;

#pragma unroll
  for (int s = 0; s < 8; ++s) {
#pragma unroll
    for (int t = 0; t < 25; ++t) {
      int col = t * 128 + w * 16 + ln;
      short8 bf = *(const short8*)(Bp + ((size_t)(s * 3200 + col) * 4 + grp) * 8);
      acc[t] = __builtin_amdgcn_mfma_f32_16x16x32_bf16(af[s], bf, acc[t], 0, 0, 0);
    }
  }

  int col4 = tid & 31, rw = tid >> 5;  // store mapping: 32 x f32x4  X  16 rows
  int grow = row0 + rw;
#pragma unroll
  for (int t = 0; t < 25; ++t) {
    // D frag: row = grp*4+rr, col(strip) = w*16+ln
    float bv = bias[t * 128 + w * 16 + ln];
#pragma unroll
    for (int rr = 0; rr < 4; ++rr)
      lt[t & 1][grp * 4 + rr][w * 16 + ln] = acc[t][rr] + bv;
    __syncthreads();
    f32x4 v = *(const f32x4*)&lt[t & 1][rw][col4 * 4];
    int gcn0 = t * 128 + col4 * 4;
    if (gcn0 >= 76 && gcn0 + 4 <= 3076) {
      __builtin_nontemporal_store(v, (f32x4*)(out + 3750000ull + (size_t)grow * 3000 + (gcn0 - 76)));
    } else {
#pragma unroll
      for (int j = 0; j < 4; ++j) {
        int gcn = gcn0 + j;
        if (gcn >= 3076) continue;
        size_t offo;
        if (gcn < 30)      offo = (size_t)grow * 30 + gcn;
        else if (gcn < 55) offo = 1500000ull + (size_t)grow * 25 + (gcn - 30);
        else if (gcn < 75) offo = 2750000ull + (size_t)grow * 20 + (gcn - 55);
        else if (gcn == 75) continue;
        else               offo = 3750000ull + (size_t)grow * 3000 + (gcn - 76);
        out[offo] = v[j];
      }
    }
  }
}

// ---------------- launch ----------------

extern "C" void kernel_launch(void* const* d_in, const int* in_sizes, int n_in,
                              void* d_out, int out_size, void* d_ws, size_t ws_size,
                              hipStream_t stream) {
  const float* x  = (const float*)d_in[0];
  const int* ei   = (const int*)d_in[1];
  const float* W1 = (const float*)d_in[2];
  const float* b1 = (const float*)d_in[3];
  const float* W2 = (const float*)d_in[4];
  const float* b2 = (const float*)d_in[5];
  const float* Wt = (const float*)d_in[6];
  const float* bt = (const float*)d_in[7];
  const float* Ws = (const float*)d_in[8];
  const float* bs = (const float*)d_in[9];
  const float* Wf = (const float*)d_in[10];
  const float* bf_ = (const float*)d_in[11];
  const float* Wa = (const float*)d_in[12];
  const float* ba = (const float*)d_in[13];

  char* ws = (char*)d_ws;
  size_t off = 0;
  auto alloc = [&](size_t bytes) {
    void* p = ws + off;
    off = (off + bytes + 255) & ~(size_t)255;
    return p;
  };
  int* deg    = (int*)alloc(N_NODES * 4);
  int* cur    = (int*)alloc(N_NODES * 4);
  float* dinv = (float*)alloc(N_NODES * 4);
  int* rowptr = (int*)alloc((N_NODES + 1) * 4);
  int* csr    = (int*)alloc((size_t)N_EDGES * 4);
  unsigned short* xb = (unsigned short*)alloc((size_t)N_NODES * 128 * 2);
  unsigned short* A1 = (unsigned short*)alloc((size_t)N_NODES * 128 * 2);
  unsigned short* h  = (unsigned short*)alloc((size_t)N_NODES * 512 * 2);
  unsigned short* t  = (unsigned short*)alloc((size_t)N_NODES * 256 * 2);
  unsigned short* g  = h;  // alias: h dead after gemm1
  unsigned short* Bp0 = (unsigned short*)alloc((size_t)512 * 128 * 2);
  unsigned short* Bp1 = (unsigned short*)alloc((size_t)256 * 512 * 2);
  unsigned short* BpH = (unsigned short*)alloc((size_t)3200 * 256 * 2);
  float* bcat = (float*)alloc(3200 * 4);

  const int NP = (N_NODES + 63) / 64;  // 782 row panels

  hipMemsetAsync(deg, 0, N_NODES * 4, stream);
  hipMemsetAsync(cur, 0, N_NODES * 4, stream);
  k_deg<<<(N_EDGES + 255) / 256, 256, 0, stream>>>(ei, deg);
  k_dinv<<<(N_NODES + 255) / 256, 256, 0, stream>>>(deg, dinv);
  k_scan<<<1, 1024, 0, stream>>>(deg, rowptr);
  k_fill<<<(N_EDGES + 255) / 256, 256, 0, stream>>>(ei, rowptr, cur, csr);
  k_cvt<<<(N_NODES * 128 / 4 + 255) / 256, 256, 0, stream>>>(x, xb);
  k_packW<<<(512 * 128 / 8 + 255) / 256, 256, 0, stream>>>(W1, Bp0, 4, 512);
  k_packW<<<(256 * 512 / 8 + 255) / 256, 256, 0, stream>>>(W2, Bp1, 16, 256);
  k_packH<<<(102400 + 255) / 256, 256, 0, stream>>>(Wt, Ws, Wf, Wa, bt, bs, bf_, ba, BpH, bcat);
  k_agg1<<<(N_NODES + 3) / 4, 256, 0, stream>>>(xb, dinv, rowptr, csr, A1);
  gemm_c<4, 4, 0><<<NP * 4, 256, 0, stream>>>(A1, Bp0, b1, h, N_NODES, NP);
  gemm_c<16, 2, 1><<<NP * 2, 256, 0, stream>>>(h, Bp1, nullptr, t, N_NODES, NP);
  k_agg2<<<(N_NODES + 3) / 4, 256, 0, stream>>>(t, dinv, rowptr, csr, b2, g);
  gemm_h<<<N_NODES / 16, 512, 0, stream>>>(g, BpH, bcat, (float*)d_out);
}

// Round 9
// 714.997 us; speedup vs baseline: 1.1241x; 1.1241x over previous
//
#include <hip/hip_runtime.h>

#define N_NODES 50000
#define N_EDGES 800000

typedef __attribute__((ext_vector_type(8))) short short8;
typedef __attribute__((ext_vector_type(4))) float f32x4;
typedef __attribute__((ext_vector_type(4))) unsigned short u16x4;

__device__ inline unsigned short f2b(float f) {
  union { float f; unsigned int u; } c; c.f = f;
  unsigned int u = c.u;
  u += 0x7FFF + ((u >> 16) & 1);   // round-to-nearest-even
  return (unsigned short)(u >> 16);
}
__device__ inline float b2f_lo(unsigned int u) {
  union { unsigned int u; float f; } c; c.u = u << 16; return c.f;
}
__device__ inline float b2f_hi(unsigned int u) {
  union { unsigned int u; float f; } c; c.u = u & 0xFFFF0000u; return c.f;
}

// ---------------- graph preprocessing ----------------
// edge_index arrives as int32 [2][E]

__global__ void k_deg(const int* __restrict__ ei, int* __restrict__ deg) {
  int e = blockIdx.x * 256 + threadIdx.x;
  if (e < N_EDGES) atomicAdd(&deg[ei[N_EDGES + e]], 1);
}

// single-block shfl-based exclusive scan; also emits dinv = rsqrt(deg+1)
__global__ void k_scan(const int* __restrict__ cnt, int* __restrict__ rowptr,
                       float* __restrict__ dinv) {
  __shared__ int wsum[16];
  int tid = threadIdx.x, lane = tid & 63, wv = tid >> 6;
  int carry = 0;
  for (int base = 0; base < N_NODES; base += 1024) {
    int i = base + tid;
    int v = (i < N_NODES) ? cnt[i] : 0;
    if (i < N_NODES) dinv[i] = rsqrtf((float)(v + 1));
    int s = v;
#pragma unroll
    for (int off = 1; off < 64; off <<= 1) {
      int u = __shfl_up(s, off, 64);
      if (lane >= off) s += u;
    }
    if (lane == 63) wsum[wv] = s;
    __syncthreads();
    int ws = (lane < 16) ? wsum[lane] : 0;
#pragma unroll
    for (int off = 1; off < 16; off <<= 1) {
      int u = __shfl_up(ws, off, 64);
      if (lane >= off && lane < 16) ws += u;
    }
    int wOff = (wv == 0) ? 0 : __shfl(ws, wv - 1, 64);
    int total = __shfl(ws, 15, 64);
    if (i < N_NODES) rowptr[i] = carry + wOff + (s - v);
    carry += total;
    __syncthreads();
  }
  if (tid == 0) rowptr[N_NODES] = carry;
}

__global__ void k_fill(const int* __restrict__ ei, const int* __restrict__ rowptr,
                       int* __restrict__ cur, int* __restrict__ csr) {
  int e = blockIdx.x * 256 + threadIdx.x;
  if (e < N_EDGES) {
    int d = ei[N_EDGES + e];
    int p = atomicAdd(&cur[d], 1);
    csr[rowptr[d] + p] = ei[e];
  }
}

// ---------------- fused prep: x->bf16, pack W1/W2 (chunked), pack heads ----
// Chunked B layout (16B units of 8 bf16): unit = ((chunk*KS + s)*128 + col)*4 + grp
// holds W[k = s*32+grp*8+j][gcol = chunk*128+col], j=0..7; zero pad.
// Heads packed col space: [0,30)=type [30,55)=school [55,75)=time 75=pad0
// [76,3076)=author (author base 76 => 4-float-aligned author stores).

#define CVT_UNITS (N_NODES * 128 / 4)       // 1,600,000
#define PW1_UNITS (4 * 4 * 512)             // N=512,KS=4 -> 8192
#define PW2_UNITS (2 * 16 * 512)            // N=256,KS=16 -> 16384
#define PH_UNITS  102400                    // 25 chunks * KS=8 * 512

__global__ void k_prep(const float* __restrict__ x, unsigned short* __restrict__ xb,
                       const float* __restrict__ W1, unsigned short* __restrict__ Bp0,
                       const float* __restrict__ W2, unsigned short* __restrict__ Bp1,
                       const float* __restrict__ Wt, const float* __restrict__ Ws,
                       const float* __restrict__ Wf, const float* __restrict__ Wa,
                       const float* __restrict__ bt, const float* __restrict__ bs,
                       const float* __restrict__ bfv, const float* __restrict__ ba,
                       unsigned short* __restrict__ BpH, float* __restrict__ bcat) {
  int idx = blockIdx.x * 256 + threadIdx.x;
  if (idx < CVT_UNITS) {
    float4 v = ((const float4*)x)[idx];
    ushort4 o; o.x = f2b(v.x); o.y = f2b(v.y); o.z = f2b(v.z); o.w = f2b(v.w);
    ((ushort4*)xb)[idx] = o;
    return;
  }
  idx -= CVT_UNITS;
  if (idx < PW1_UNITS) {  // W1: K=128 (KS=4), N=512 (4 chunks)
    const int KS = 4, N = 512;
    int grp = idx & 3, col = (idx >> 2) & 127;
    int rest = idx >> 9;
    int s = rest % KS, chunk = rest / KS;
    int gcol = chunk * 128 + col, k0 = s * 32 + grp * 8;
    unsigned short o[8];
#pragma unroll
    for (int j = 0; j < 8; ++j) o[j] = f2b(W1[(size_t)(k0 + j) * N + gcol]);
    *(short8*)(Bp0 + (size_t)idx * 8) = *(short8*)o;
    return;
  }
  idx -= PW1_UNITS;
  if (idx < PW2_UNITS) {  // W2: K=512 (KS=16), N=256 (2 chunks)
    const int KS = 16, N = 256;
    int grp = idx & 3, col = (idx >> 2) & 127;
    int rest = idx >> 9;
    int s = rest % KS, chunk = rest / KS;
    int gcol = chunk * 128 + col, k0 = s * 32 + grp * 8;
    unsigned short o[8];
#pragma unroll
    for (int j = 0; j < 8; ++j) o[j] = f2b(W2[(size_t)(k0 + j) * N + gcol]);
    *(short8*)(Bp1 + (size_t)idx * 8) = *(short8*)o;
    return;
  }
  idx -= PW2_UNITS;
  if (idx < PH_UNITS) {   // heads: K=256 (KS=8), 25 chunks, chunked layout
    const int KS = 8;
    int grp = idx & 3, col = (idx >> 2) & 127;
    int rest = idx >> 9;
    int s = rest % KS, chunk = rest / KS;
    int gcol = chunk * 128 + col, k0 = s * 32 + grp * 8;
    const float* W = Wt; int ld = 30, c = 0;
    bool ok = true;
    if (gcol < 30)                        { W = Wt; ld = 30;   c = gcol; }
    else if (gcol < 55)                   { W = Ws; ld = 25;   c = gcol - 30; }
    else if (gcol < 75)                   { W = Wf; ld = 20;   c = gcol - 55; }
    else if (gcol >= 76 && gcol < 3076)   { W = Wa; ld = 3000; c = gcol - 76; }
    else                                  { ok = false; }
    unsigned short o[8];
#pragma unroll
    for (int j = 0; j < 8; ++j)
      o[j] = ok ? f2b(W[(size_t)(k0 + j) * ld + c]) : 0;
    *(short8*)(BpH + (size_t)idx * 8) = *(short8*)o;
    if (idx < 3200) {
      float v = 0.f;
      if (idx < 30)                      v = bt[idx];
      else if (idx < 55)                 v = bs[idx - 30];
      else if (idx < 75)                 v = bfv[idx - 55];
      else if (idx >= 76 && idx < 3076)  v = ba[idx - 76];
      bcat[idx] = v;
    }
  }
}

// ---------------- aggregation (wave per node, 4 waves/block, x8 unroll) ----

__global__ void k_agg1(const unsigned short* __restrict__ xb, const float* __restrict__ dinv,
                       const int* __restrict__ rowptr, const int* __restrict__ csr,
                       unsigned short* __restrict__ A1) {
  int n = blockIdx.x * 4 + (threadIdx.x >> 6);
  if (n >= N_NODES) return;
  int l = threadIdx.x & 63;
  float dn = dinv[n];
  const unsigned int* x2 = (const unsigned int*)xb;
  unsigned int sv = x2[(size_t)n * 64 + l];
  float a0 = b2f_lo(sv) * dn * dn, a1 = b2f_hi(sv) * dn * dn;
  int e = rowptr[n], e1 = rowptr[n + 1];
  for (; e + 8 <= e1; e += 8) {
    int si[8]; float cf[8]; unsigned int v[8];
#pragma unroll
    for (int j = 0; j < 8; ++j) si[j] = csr[e + j];
#pragma unroll
    for (int j = 0; j < 8; ++j) cf[j] = dinv[si[j]] * dn;
#pragma unroll
    for (int j = 0; j < 8; ++j) v[j] = x2[(size_t)si[j] * 64 + l];
#pragma unroll
    for (int j = 0; j < 8; ++j) { a0 += b2f_lo(v[j]) * cf[j]; a1 += b2f_hi(v[j]) * cf[j]; }
  }
  for (; e + 4 <= e1; e += 4) {
    int s0 = csr[e], s1 = csr[e + 1], s2 = csr[e + 2], s3 = csr[e + 3];
    float c0 = dinv[s0] * dn, c1 = dinv[s1] * dn, c2 = dinv[s2] * dn, c3 = dinv[s3] * dn;
    unsigned int v0 = x2[(size_t)s0 * 64 + l];
    unsigned int v1 = x2[(size_t)s1 * 64 + l];
    unsigned int v2 = x2[(size_t)s2 * 64 + l];
    unsigned int v3 = x2[(size_t)s3 * 64 + l];
    a0 += b2f_lo(v0) * c0 + b2f_lo(v1) * c1 + b2f_lo(v2) * c2 + b2f_lo(v3) * c3;
    a1 += b2f_hi(v0) * c0 + b2f_hi(v1) * c1 + b2f_hi(v2) * c2 + b2f_hi(v3) * c3;
  }
  for (; e < e1; ++e) {
    int s = csr[e];
    float c = dinv[s] * dn;
    unsigned int v = x2[(size_t)s * 64 + l];
    a0 += b2f_lo(v) * c; a1 += b2f_hi(v) * c;
  }
  unsigned int pk = (unsigned int)f2b(a0) | ((unsigned int)f2b(a1) << 16);
  ((unsigned int*)A1)[(size_t)n * 64 + l] = pk;
}

__global__ void k_agg2(const unsigned short* __restrict__ t, const float* __restrict__ dinv,
                       const int* __restrict__ rowptr, const int* __restrict__ csr,
                       const float* __restrict__ b2, unsigned short* __restrict__ g) {
  int n = blockIdx.x * 4 + (threadIdx.x >> 6);
  if (n >= N_NODES) return;
  int l = threadIdx.x & 63;
  float dn = dinv[n];
  const uint2* t4 = (const uint2*)t;
  uint2 sv = t4[(size_t)n * 64 + l];
  float a0 = b2f_lo(sv.x) * dn * dn, a1 = b2f_hi(sv.x) * dn * dn;
  float a2 = b2f_lo(sv.y) * dn * dn, a3 = b2f_hi(sv.y) * dn * dn;
  int e = rowptr[n], e1 = rowptr[n + 1];
  for (; e + 8 <= e1; e += 8) {
    int si[8]; float cf[8]; uint2 v[8];
#pragma unroll
    for (int j = 0; j < 8; ++j) si[j] = csr[e + j];
#pragma unroll
    for (int j = 0; j < 8; ++j) cf[j] = dinv[si[j]] * dn;
#pragma unroll
    for (int j = 0; j < 8; ++j) v[j] = t4[(size_t)si[j] * 64 + l];
#pragma unroll
    for (int j = 0; j < 8; ++j) {
      a0 += b2f_lo(v[j].x) * cf[j]; a1 += b2f_hi(v[j].x) * cf[j];
      a2 += b2f_lo(v[j].y) * cf[j]; a3 += b2f_hi(v[j].y) * cf[j];
    }
  }
  for (; e + 4 <= e1; e += 4) {
    int s0 = csr[e], s1 = csr[e + 1], s2 = csr[e + 2], s3 = csr[e + 3];
    float c0 = dinv[s0] * dn, c1 = dinv[s1] * dn, c2 = dinv[s2] * dn, c3 = dinv[s3] * dn;
    uint2 v0 = t4[(size_t)s0 * 64 + l];
    uint2 v1 = t4[(size_t)s1 * 64 + l];
    uint2 v2 = t4[(size_t)s2 * 64 + l];
    uint2 v3 = t4[(size_t)s3 * 64 + l];
    a0 += b2f_lo(v0.x) * c0 + b2f_lo(v1.x) * c1 + b2f_lo(v2.x) * c2 + b2f_lo(v3.x) * c3;
    a1 += b2f_hi(v0.x) * c0 + b2f_hi(v1.x) * c1 + b2f_hi(v2.x) * c2 + b2f_hi(v3.x) * c3;
    a2 += b2f_lo(v0.y) * c0 + b2f_lo(v1.y) * c1 + b2f_lo(v2.y) * c2 + b2f_lo(v3.y) * c3;
    a3 += b2f_hi(v0.y) * c0 + b2f_hi(v1.y) * c1 + b2f_hi(v2.y) * c2 + b2f_hi(v3.y) * c3;
  }
  for (; e < e1; ++e) {
    int s = csr[e];
    float c = dinv[s] * dn;
    uint2 v = t4[(size_t)s * 64 + l];
    a0 += b2f_lo(v.x) * c; a1 += b2f_hi(v.x) * c;
    a2 += b2f_lo(v.y) * c; a3 += b2f_hi(v.y) * c;
  }
  int d0 = l * 4;
  a0 += b2[d0]; a1 += b2[d0 + 1]; a2 += b2[d0 + 2]; a3 += b2[d0 + 3];
  ushort4 o; o.x = f2b(a0); o.y = f2b(a1); o.z = f2b(a2); o.w = f2b(a3);
  ((ushort4*)g)[(size_t)n * 64 + l] = o;
}

// ---------------- one-chunk-per-block MFMA GEMM (round-5 config) ----------
// Block = 64 rows x 128 cols, full K unrolled; XCD-chunked bijective swizzle.
// Full-height lt[64][132] transpose; nt stores for the fp32 heads stream,
// cached stores for h/t (re-read by next kernel).
// EPI 0: bf16 relu(acc+bias) ; EPI 1: bf16 acc ; EPI 2: heads fp32 segmented.

template <int KSTEPS, int NCHUNKS, int EPI>
__global__ __launch_bounds__(256)
void gemm_c(const unsigned short* __restrict__ A, const unsigned short* __restrict__ Bp,
            const float* __restrict__ bias, void* __restrict__ out, int M, int npanels) {
  __shared__ float lt[64][132];
  const int K = KSTEPS * 32;
  int nwg = npanels * NCHUNKS;
  int orig = blockIdx.x;
  int q = nwg >> 3, r = nwg & 7, xcd = orig & 7;
  int l = (xcd < r ? xcd * (q + 1) : r * (q + 1) + (xcd - r) * q) + (orig >> 3);
  int panel = l / NCHUNKS, chunk = l - panel * NCHUNKS;
  int tid = threadIdx.x, lane = tid & 63, w = tid >> 6;
  int ln = lane & 15, grp = lane >> 4;
  int row0 = panel * 64;

  int arow[4];
#pragma unroll
  for (int m = 0; m < 4; ++m) {
    int gr = row0 + m * 16 + ln;
    arow[m] = gr < M ? gr : M - 1;
  }

  f32x4 acc[4][2];
  f32x4 z = {0.f, 0.f, 0.f, 0.f};
#pragma unroll
  for (int m = 0; m < 4; ++m) { acc[m][0] = z; acc[m][1] = z; }

#pragma unroll 4
  for (int s = 0; s < KSTEPS; ++s) {
    short8 bfr[2];
#pragma unroll
    for (int n = 0; n < 2; ++n) {
      size_t unit = ((size_t)(chunk * KSTEPS + s) * 128 + (w * 32 + n * 16 + ln)) * 4 + grp;
      bfr[n] = *(const short8*)(Bp + unit * 8);
    }
    short8 am[4];
#pragma unroll
    for (int m = 0; m < 4; ++m)
      am[m] = *(const short8*)(A + (size_t)arow[m] * K + s * 32 + grp * 8);
#pragma unroll
    for (int m = 0; m < 4; ++m)
#pragma unroll
      for (int n = 0; n < 2; ++n)
        acc[m][n] = __builtin_amdgcn_mfma_f32_16x16x32_bf16(am[m], bfr[n], acc[m][n], 0, 0, 0);
  }

  // bias + relu in regs, then transpose through LDS
  int c0 = chunk * 128;
#pragma unroll
  for (int n = 0; n < 2; ++n) {
    int gcn = c0 + w * 32 + n * 16 + ln;
    float bv = (EPI == 1) ? 0.f : bias[gcn];
#pragma unroll
    for (int m = 0; m < 4; ++m)
#pragma unroll
      for (int rr = 0; rr < 4; ++rr) {
        float v = acc[m][n][rr] + bv;
        if (EPI == 0) v = v > 0.f ? v : 0.f;
        lt[m * 16 + grp * 4 + rr][w * 32 + n * 16 + ln] = v;
      }
  }
  __syncthreads();

  // coalesced store: thread covers one float4 group; 8 rounds of 8 rows
  int col4 = tid & 31, rowi = tid >> 5;
#pragma unroll
  for (int rr = 0; rr < 8; ++rr) {
    int rw = rr * 8 + rowi;
    int grow = row0 + rw;
    if (grow >= M) continue;
    f32x4 v = *(const f32x4*)&lt[rw][col4 * 4];
    if (EPI == 2) {
      int gcn0 = c0 + col4 * 4;
      float* o = (float*)out;
      if (gcn0 >= 76 && gcn0 + 4 <= 3076) {
        __builtin_nontemporal_store(v, (f32x4*)(o + 3750000ull + (size_t)grow * 3000 + (gcn0 - 76)));
      } else {
#pragma unroll
        for (int j = 0; j < 4; ++j) {
          int gcn = gcn0 + j;
          if (gcn >= 3076) continue;
          size_t offo;
          if (gcn < 30)      offo = (size_t)grow * 30 + gcn;
          else if (gcn < 55) offo = 1500000ull + (size_t)grow * 25 + (gcn - 30);
          else if (gcn < 75) offo = 2750000ull + (size_t)grow * 20 + (gcn - 55);
          else if (gcn == 75) continue;
          else               offo = 3750000ull + (size_t)grow * 3000 + (gcn - 76);
          o[offo] = v[j];
        }
      }
    } else {
      const int NOUT = NCHUNKS * 128;
      u16x4 b;
      b[0] = f2b(v[0]); b[1] = f2b(v[1]); b[2] = f2b(v[2]); b[3] = f2b(v[3]);
      *(u16x4*)((unsigned short*)out + (size_t)grow * NOUT + c0 + col4 * 4) = b;
    }
  }
}

// ---------------- launch ----------------

extern "C" void kernel_launch(void* const* d_in, const int* in_sizes, int n_in,
                              void* d_out, int out_size, void* d_ws, size_t ws_size,
                              hipStream_t stream) {
  const float* x  = (const float*)d_in[0];
  const int* ei   = (const int*)d_in[1];
  const float* W1 = (const float*)d_in[2];
  const float* b1 = (const float*)d_in[3];
  const float* W2 = (const float*)d_in[4];
  const float* b2 = (const float*)d_in[5];
  const float* Wt = (const float*)d_in[6];
  const float* bt = (const float*)d_in[7];
  const float* Ws = (const float*)d_in[8];
  const float* bs = (const float*)d_in[9];
  const float* Wf = (const float*)d_in[10];
  const float* bf_ = (const float*)d_in[11];
  const float* Wa = (const float*)d_in[12];
  const float* ba = (const float*)d_in[13];

  char* ws = (char*)d_ws;
  size_t off = 0;
  auto alloc = [&](size_t bytes) {
    void* p = ws + off;
    off = (off + bytes + 255) & ~(size_t)255;
    return p;
  };
  int* deg    = (int*)alloc(N_NODES * 4);
  int* cur    = (int*)alloc(N_NODES * 4);
  float* dinv = (float*)alloc(N_NODES * 4);
  int* rowptr = (int*)alloc((N_NODES + 1) * 4);
  int* csr    = (int*)alloc((size_t)N_EDGES * 4);
  unsigned short* xb = (unsigned short*)alloc((size_t)N_NODES * 128 * 2);
  unsigned short* A1 = (unsigned short*)alloc((size_t)N_NODES * 128 * 2);
  unsigned short* h  = (unsigned short*)alloc((size_t)N_NODES * 512 * 2);
  unsigned short* t  = (unsigned short*)alloc((size_t)N_NODES * 256 * 2);
  unsigned short* g  = h;  // alias: h dead after gemm1
  unsigned short* Bp0 = (unsigned short*)alloc((size_t)512 * 128 * 2);
  unsigned short* Bp1 = (unsigned short*)alloc((size_t)256 * 512 * 2);
  unsigned short* BpH = (unsigned short*)alloc((size_t)3200 * 256 * 2);
  float* bcat = (float*)alloc(3200 * 4);

  const int NP = (N_NODES + 63) / 64;  // 782 row panels
  const int PREP_UNITS = CVT_UNITS + PW1_UNITS + PW2_UNITS + PH_UNITS;

  hipMemsetAsync(deg, 0, N_NODES * 4, stream);
  hipMemsetAsync(cur, 0, N_NODES * 4, stream);
  k_deg<<<(N_EDGES + 255) / 256, 256, 0, stream>>>(ei, deg);
  k_scan<<<1, 1024, 0, stream>>>(deg, rowptr, dinv);
  k_fill<<<(N_EDGES + 255) / 256, 256, 0, stream>>>(ei, rowptr, cur, csr);
  k_prep<<<(PREP_UNITS + 255) / 256, 256, 0, stream>>>(x, xb, W1, Bp0, W2, Bp1,
      Wt, Ws, Wf, Wa, bt, bs, bf_, ba, BpH, bcat);
  k_agg1<<<(N_NODES + 3) / 4, 256, 0, stream>>>(xb, dinv, rowptr, csr, A1);
  gemm_c<4, 4, 0><<<NP * 4, 256, 0, stream>>>(A1, Bp0, b1, h, N_NODES, NP);
  gemm_c<16, 2, 1><<<NP * 2, 256, 0, stream>>>(h, Bp1, nullptr, t, N_NODES, NP);
  k_agg2<<<(N_NODES + 3) / 4, 256, 0, stream>>>(t, dinv, rowptr, csr, b2, g);
  gemm_c<8, 25, 2><<<NP * 25, 256, 0, stream>>>(g, BpH, bcat, d_out, N_NODES, NP);
}